// Round 15
// baseline (426.585 us; speedup 1.0000x reference)
//
#include <hip/hip_runtime.h>

#define D 64
#define NGRAPH 128
#define NCLS 10
#define BN_EPS 1e-5f
#define BUCK_SZ 512   // dsts per bucket (2^9)
#define EPB 8192      // edges per block in pass 1

typedef __attribute__((ext_vector_type(8))) __bf16 bf16x8;
typedef __attribute__((ext_vector_type(4))) float floatx4;

union BF8 { bf16x8 v; ushort u[8]; };

// fp32 -> bf16 round-to-nearest-even (bits).
__device__ __forceinline__ unsigned f2bf_rne(float f) {
  unsigned u = __float_as_uint(f);
  return (u + 0x7FFFu + ((u >> 16) & 1u)) >> 16;
}
__device__ __forceinline__ unsigned pack2bf(float a, float b) {
  return f2bf_rne(a) | (f2bf_rne(b) << 16);
}
// Unpack 4 packed bf16 (uint2) -> float4.
__device__ __forceinline__ float4 bf4_to_f4(uint2 u) {
  float4 r;
  r.x = __uint_as_float(u.x << 16);
  r.y = __uint_as_float(u.x & 0xFFFF0000u);
  r.z = __uint_as_float(u.y << 16);
  r.w = __uint_as_float(u.y & 0xFFFF0000u);
  return r;
}

// BN scale/shift for feature f from raw stats (sum, sumsq).
__device__ __forceinline__ void bn_sc_sh(
    const float* __restrict__ stats, const float* __restrict__ gamma,
    const float* __restrict__ beta, float fN, int f, float* sc, float* sh) {
  float mean = stats[f] / fN;
  float var = stats[D + f] / fN - mean * mean;
  float s = gamma[f] * rsqrtf(var + BN_EPS);
  *sc = s;
  *sh = beta[f] - mean * s;
}

// Split 8 fp32 into bf16 hi (truncation) + bf16 lo (residual, truncated).
__device__ __forceinline__ void split8(float4 a, float4 b,
                                       bf16x8* hi, bf16x8* lo) {
  float f[8] = {a.x, a.y, a.z, a.w, b.x, b.y, b.z, b.w};
  BF8 H, L;
#pragma unroll
  for (int t = 0; t < 8; t++) {
    unsigned u = __float_as_uint(f[t]);
    H.u[t] = (ushort)(u >> 16);
    float hf = __uint_as_float(u & 0xFFFF0000u);
    float lf = f[t] - hf;
    L.u[t] = (ushort)(__float_as_uint(lf) >> 16);
  }
  *hi = H.v;
  *lo = L.v;
}

// ===========================================================================
// CSR build pass 1: block-aggregated bucket sort of edges.
// ===========================================================================
__global__ __launch_bounds__(256) void bucket_scatter_kernel(
    const int* __restrict__ ei, int* __restrict__ gcnt, int* __restrict__ pk,
    int E, int capB, int nbuck) {
  __shared__ int hist[256];
  __shared__ int base[256];
  int t = threadIdx.x;
  int e0 = blockIdx.x * EPB;
  int e1 = min(e0 + EPB, E);
  hist[t] = 0;
  __syncthreads();
  for (int e = e0 + t; e < e1; e += 256)
    atomicAdd(&hist[ei[E + e] >> 9], 1);
  __syncthreads();
  int h = hist[t];
  if (t < nbuck && h > 0) base[t] = atomicAdd(&gcnt[t], h);
  hist[t] = 0;  // reuse as per-bucket cursor
  __syncthreads();
  for (int e = e0 + t; e < e1; e += 256) {
    int s = ei[e];
    int d = ei[E + e];
    int b = d >> 9;
    int pos = base[b] + atomicAdd(&hist[b], 1);
    if (pos < capB) pk[(size_t)b * capB + pos] = (s << 9) | (d & (BUCK_SZ - 1));
  }
}

// Exclusive scan of per-bucket totals (nbuck <= 256); row_start[N] = total.
__global__ void bucket_scan_kernel(const int* __restrict__ gcnt,
                                   int* __restrict__ bstart,
                                   int* __restrict__ row_start,
                                   int nbuck, int N, int capB) {
  __shared__ int s[256];
  int t = threadIdx.x;
  int v = (t < nbuck) ? min(gcnt[t], capB) : 0;
  s[t] = v;
  __syncthreads();
  for (int off = 1; off < 256; off <<= 1) {
    int add = (t >= off) ? s[t - off] : 0;
    __syncthreads();
    s[t] += add;
    __syncthreads();
  }
  if (t < nbuck) bstart[t] = s[t] - v;
  if (t == 0) {
    bstart[nbuck] = s[255];
    row_start[N] = s[255];
  }
}

// Pass 2: one block per bucket: LDS histogram, scan, place.
__global__ __launch_bounds__(256) void bucket_place_kernel(
    const int* __restrict__ pk, const int* __restrict__ gcnt,
    const int* __restrict__ bstart, int* __restrict__ row_start,
    int* __restrict__ csr_src, int N, int capB) {
  __shared__ int hist[BUCK_SZ];
  __shared__ int scn[256];
  __shared__ int cur[BUCK_SZ];
  int b = blockIdx.x;
  int t = threadIdx.x;
  hist[t] = 0;
  hist[t + 256] = 0;
  int cnt = min(gcnt[b], capB);
  const int* seg = pk + (size_t)b * capB;
  __syncthreads();
  for (int e = t; e < cnt; e += 256)
    atomicAdd(&hist[seg[e] & (BUCK_SZ - 1)], 1);
  __syncthreads();
  scn[t] = hist[2 * t] + hist[2 * t + 1];
  __syncthreads();
  for (int off = 1; off < 256; off <<= 1) {
    int add = (t >= off) ? scn[t - off] : 0;
    __syncthreads();
    scn[t] += add;
    __syncthreads();
  }
  int base = bstart[b];
  int ex = (t == 0) ? 0 : scn[t - 1];
  int c0 = base + ex;
  int c1 = c0 + hist[2 * t];
  cur[2 * t] = c0;
  cur[2 * t + 1] = c1;
  int dst0 = b * BUCK_SZ + 2 * t;
  if (dst0 < N) row_start[dst0] = c0;
  if (dst0 + 1 < N) row_start[dst0 + 1] = c1;
  __syncthreads();
  for (int e = t; e < cnt; e += 256) {
    int p = seg[e];
    int slot = atomicAdd(&cur[p & (BUCK_SZ - 1)], 1);
    csr_src[slot] = p >> 9;
  }
}

// ===========================================================================
// Weight split+swizzle prep (once).
// ===========================================================================
__global__ __launch_bounds__(256) void wsplit_kernel(
    const float* __restrict__ Wrel, const float* __restrict__ Wroot,
    ushort* __restrict__ wfrag) {
  int l = blockIdx.x;  // 0..2
  const float* Wr = Wrel + l * 4096;
  const float* Wo = Wroot + l * 4096;
  ushort* base = wfrag + l * 16384;
  for (int slot = threadIdx.x; slot < 1024; slot += 256) {
    int kt = slot >> 8, nt = (slot >> 6) & 3, lane = slot & 63;
    int quad = lane >> 4, c = lane & 15;
    ushort* ph = base + (((kt * 4 + nt) * 2 + 0) * 64 + lane) * 8;
    ushort* pl = base + (((kt * 4 + nt) * 2 + 1) * 64 + lane) * 8;
#pragma unroll
    for (int j = 0; j < 8; j++) {
      int k = kt * 32 + quad * 8 + j;
      int n = nt * 16 + c;
      float w = (k < 64) ? Wr[k * 64 + n] : Wo[(k - 64) * 64 + n];
      unsigned u = __float_as_uint(w);
      ph[j] = (ushort)(u >> 16);
      float lf = w - __uint_as_float(u & 0xFFFF0000u);
      pl[j] = (ushort)(__float_as_uint(lf) >> 16);
    }
  }
}

// ===========================================================================
// x -> packed bf16 (RNE), once per call. 8 elements/thread.
// ===========================================================================
__global__ __launch_bounds__(256) void xprep_kernel(
    const float* __restrict__ x, ushort* __restrict__ xbf, int n) {
  int base = (blockIdx.x * 256 + threadIdx.x) * 8;
  if (base >= n) return;
  float4 a = *(const float4*)(x + base);
  float4 b = *(const float4*)(x + base + 4);
  uint4 o;
  o.x = pack2bf(a.x, a.y);
  o.y = pack2bf(a.z, a.w);
  o.z = pack2bf(b.x, b.y);
  o.w = pack2bf(b.z, b.w);
  *(uint4*)(xbf + base) = o;
}

// ===========================================================================
// Gather v5: one wave per dst row; lane = (edge slot es 0..7, feature-half
// fh 0..7). ONE uint4 (16B = 8 bf16) load covers a row-half; 8 edges per
// load instruction (2x fewer than v3's 8B layout). Row indices preloaded in
// one coalesced load; addresses via __shfl; clamped index + mask-multiply.
// Cross-slot shfl reduce (stride 8/16/32); es==0 lanes write the fp32 msg
// row. BN scale/shift computed INLINE from prev layer's raw stats (apply=1).
// ===========================================================================
__global__ __launch_bounds__(256) void gather_kernel(
    const ushort* __restrict__ xbf, const int* __restrict__ csr_src,
    const int* __restrict__ row_start, const float* __restrict__ stats_prev,
    const float* __restrict__ gamma, const float* __restrict__ beta,
    float fN, int apply, float* __restrict__ msg, int N) {
  int i = blockIdx.x * 4 + (threadIdx.x >> 6);
  int lane = threadIdx.x & 63;
  int es = lane >> 3;        // edge slot 0..7
  int f = (lane & 7) << 3;   // feature-half base (8 features)
  if (i >= N) return;
  int e0 = row_start[i], e1 = row_start[i + 1];
  int cnt = e1 - e0;
  int myidx = csr_src[e0 + lane];  // coalesced; overread lands in pk (ours)

  float sc[8], sh[8];
  if (apply) {
#pragma unroll
    for (int k = 0; k < 8; k++)
      bn_sc_sh(stats_prev, gamma, beta, fN, f + k, &sc[k], &sh[k]);
  }

  float acc[8] = {0.f, 0.f, 0.f, 0.f, 0.f, 0.f, 0.f, 0.f};
  int cnt64 = min(cnt, 64);
  for (int base = 0; base < cnt64; base += 16) {
    int j0 = base + es;       // this slot's 2 edges: j0, j0+8
    int j1 = base + 8 + es;
    int s0 = __shfl(myidx, j0);
    int s1 = __shfl(myidx, j1);
    float m0 = (j0 < cnt) ? 1.f : 0.f;
    float m1 = (j1 < cnt) ? 1.f : 0.f;
    s0 = (j0 < cnt) ? s0 : 0;  // clamp address: no OOB deref
    s1 = (j1 < cnt) ? s1 : 0;
    uint4 u0 = *(const uint4*)(xbf + (size_t)s0 * D + f);
    uint4 u1 = *(const uint4*)(xbf + (size_t)s1 * D + f);
    uint2 a0 = {u0.x, u0.y}, b0 = {u0.z, u0.w};
    uint2 a1 = {u1.x, u1.y}, b1 = {u1.z, u1.w};
    float4 v0l = bf4_to_f4(a0), v0h = bf4_to_f4(b0);
    float4 v1l = bf4_to_f4(a1), v1h = bf4_to_f4(b1);
    float w0[8] = {v0l.x, v0l.y, v0l.z, v0l.w, v0h.x, v0h.y, v0h.z, v0h.w};
    float w1[8] = {v1l.x, v1l.y, v1l.z, v1l.w, v1h.x, v1h.y, v1h.z, v1h.w};
    if (apply) {
#pragma unroll
      for (int k = 0; k < 8; k++)
        acc[k] += m0 * fmaxf(w0[k] * sc[k] + sh[k], 0.f)
                + m1 * fmaxf(w1[k] * sc[k] + sh[k], 0.f);
    } else {
#pragma unroll
      for (int k = 0; k < 8; k++)
        acc[k] += m0 * w0[k] + m1 * w1[k];
    }
  }

  // Rare tail: rows with degree > 64.
  for (int e = e0 + 64 + es; e < e1; e += 8) {
    uint4 u = *(const uint4*)(xbf + (size_t)csr_src[e] * D + f);
    uint2 a = {u.x, u.y}, b = {u.z, u.w};
    float4 vl = bf4_to_f4(a), vh = bf4_to_f4(b);
    float w[8] = {vl.x, vl.y, vl.z, vl.w, vh.x, vh.y, vh.z, vh.w};
    if (apply) {
#pragma unroll
      for (int k = 0; k < 8; k++) acc[k] += fmaxf(w[k] * sc[k] + sh[k], 0.f);
    } else {
#pragma unroll
      for (int k = 0; k < 8; k++) acc[k] += w[k];
    }
  }

#pragma unroll
  for (int k = 0; k < 8; k++) {
    acc[k] += __shfl_xor(acc[k], 8);
    acc[k] += __shfl_xor(acc[k], 16);
    acc[k] += __shfl_xor(acc[k], 32);
  }
  if (es == 0) {
    float4 lo = {acc[0], acc[1], acc[2], acc[3]};
    float4 hi = {acc[4], acc[5], acc[6], acc[7]};
    *(float4*)(msg + (size_t)i * D + f) = lo;
    *(float4*)(msg + (size_t)i * D + f + 4) = hi;
  }
}

// ===========================================================================
// mm via MFMA split-bf16. Root-term input: fp32 x (apply=0) or bf16 hbf +
// inline BN/ReLU from prev stats (apply=1; in-place tile-local). Outputs:
// hbf (wbf=1) and/or fp32 h (wh=1). BN stats of h accumulated into
// stats_cur (per-layer buffer, pre-zeroed).
// ===========================================================================
__global__ __launch_bounds__(256, 1) void mm_mfma_kernel(
    const float* msg, const float* xf32, const ushort* xbfin,
    const ushort* __restrict__ wfrag, const float* __restrict__ brel,
    const float* __restrict__ stats_prev, const float* __restrict__ gamma,
    const float* __restrict__ beta, float fN, int apply,
    float* h, ushort* hbf, int wh, int wbf, float* __restrict__ stats_cur,
    int N, int ntiles, int nwaves) {
  __shared__ float ssum[4][64];
  __shared__ float ssq[4][64];
  int tid = threadIdx.x;
  int lane = tid & 63;
  int wvid = tid >> 6;
  int wv = (blockIdx.x * 256 + tid) >> 6;
  int quad = lane >> 4;
  int lo4 = lane & 15;

  bf16x8 bf[4][4][2];
#pragma unroll
  for (int kt = 0; kt < 4; kt++)
#pragma unroll
    for (int nt = 0; nt < 4; nt++)
#pragma unroll
      for (int s = 0; s < 2; s++)
        bf[kt][nt][s] =
            *(const bf16x8*)(wfrag + (((kt * 4 + nt) * 2 + s) * 64 + lane) * 8);

  float bias[4];
#pragma unroll
  for (int nt = 0; nt < 4; nt++) bias[nt] = brel[nt * 16 + lo4];

  float scx[2][8], shx[2][8];
  if (apply) {
#pragma unroll
    for (int hh = 0; hh < 2; hh++)
#pragma unroll
      for (int jj = 0; jj < 8; jj++) {
        int f = hh * 32 + quad * 8 + jj;
        bn_sc_sh(stats_prev, gamma, beta, fN, f, &scx[hh][jj], &shx[hh][jj]);
      }
  }

  float psum[4] = {0.f, 0.f, 0.f, 0.f};
  float psq[4] = {0.f, 0.f, 0.f, 0.f};

  for (int t = wv; t < ntiles; t += nwaves) {
    int i0 = t * 16;
    int row = i0 + lo4;
    if (row >= N) row = N - 1;
    bf16x8 ahi[4], alo[4];
#pragma unroll
    for (int kt = 0; kt < 4; kt++) {
      float4 a, b;
      if (kt < 2) {
        const float* p = msg + (size_t)row * D + (kt & 1) * 32 + quad * 8;
        a = *(const float4*)p;
        b = *(const float4*)(p + 4);
      } else if (apply) {
        const ushort* p = xbfin + (size_t)row * D + (kt & 1) * 32 + quad * 8;
        uint4 u = *(const uint4*)p;
        uint2 ulo = {u.x, u.y}, uhi = {u.z, u.w};
        a = bf4_to_f4(ulo);
        b = bf4_to_f4(uhi);
        int hh = kt - 2;
        a.x = fmaxf(a.x * scx[hh][0] + shx[hh][0], 0.f);
        a.y = fmaxf(a.y * scx[hh][1] + shx[hh][1], 0.f);
        a.z = fmaxf(a.z * scx[hh][2] + shx[hh][2], 0.f);
        a.w = fmaxf(a.w * scx[hh][3] + shx[hh][3], 0.f);
        b.x = fmaxf(b.x * scx[hh][4] + shx[hh][4], 0.f);
        b.y = fmaxf(b.y * scx[hh][5] + shx[hh][5], 0.f);
        b.z = fmaxf(b.z * scx[hh][6] + shx[hh][6], 0.f);
        b.w = fmaxf(b.w * scx[hh][7] + shx[hh][7], 0.f);
      } else {
        const float* p = xf32 + (size_t)row * D + (kt & 1) * 32 + quad * 8;
        a = *(const float4*)p;
        b = *(const float4*)(p + 4);
      }
      split8(a, b, &ahi[kt], &alo[kt]);
    }
#pragma unroll
    for (int nt = 0; nt < 4; nt++) {
      floatx4 acc = {bias[nt], bias[nt], bias[nt], bias[nt]};
#pragma unroll
      for (int kt = 0; kt < 4; kt++) {
        acc = __builtin_amdgcn_mfma_f32_16x16x32_bf16(ahi[kt], bf[kt][nt][0],
                                                      acc, 0, 0, 0);
        acc = __builtin_amdgcn_mfma_f32_16x16x32_bf16(ahi[kt], bf[kt][nt][1],
                                                      acc, 0, 0, 0);
        acc = __builtin_amdgcn_mfma_f32_16x16x32_bf16(alo[kt], bf[kt][nt][0],
                                                      acc, 0, 0, 0);
      }
#pragma unroll
      for (int r = 0; r < 4; r++) {
        int grow = i0 + quad * 4 + r;
        if (grow < N) {
          float v = acc[r];
          size_t idx = (size_t)grow * D + nt * 16 + lo4;
          if (wh) h[idx] = v;
          if (wbf) hbf[idx] = (ushort)f2bf_rne(v);
          psum[nt] += v;
          psq[nt] += v * v;
        }
      }
    }
  }

#pragma unroll
  for (int nt = 0; nt < 4; nt++) {
    float s = psum[nt], q = psq[nt];
    s += __shfl_xor(s, 16); s += __shfl_xor(s, 32);
    q += __shfl_xor(q, 16); q += __shfl_xor(q, 32);
    if (lane < 16) { ssum[wvid][nt * 16 + lane] = s; ssq[wvid][nt * 16 + lane] = q; }
  }
  __syncthreads();
  if (tid < 64) {
    atomicAdd(&stats_cur[tid],
              ssum[0][tid] + ssum[1][tid] + ssum[2][tid] + ssum[3][tid]);
  } else if (tid < 128) {
    int c = tid - 64;
    atomicAdd(&stats_cur[D + c],
              ssq[0][c] + ssq[1][c] + ssq[2][c] + ssq[3][c]);
  }
}

// ---------------------------------------------------------------------------
// Final layer: inline BN + ReLU fused with graph mean-pool (batch sorted).
__global__ __launch_bounds__(256) void norm_relu_pool_kernel(
    const float* __restrict__ h, const float* __restrict__ stats,
    const float* __restrict__ gamma, const float* __restrict__ beta,
    float fN, const int* __restrict__ batch, float* __restrict__ pooled,
    int N) {
  int j = threadIdx.x & 63;
  int q = threadIdx.x >> 6;
  int i0 = blockIdx.x * 256;
  float sc, sh;
  bn_sc_sh(stats, gamma, beta, fN, j, &sc, &sh);
  int curg = -1;
  float acc = 0.f;
  for (int r = q; r < 256; r += 4) {
    int i = i0 + r;
    if (i >= N) break;
    int b = batch[i];
    float v = fmaxf(h[(size_t)i * D + j] * sc + sh, 0.f);
    if (b != curg) {
      if (curg >= 0) atomicAdd(&pooled[curg * D + j], acc);
      curg = b;
      acc = v;
    } else {
      acc += v;
    }
  }
  if (curg >= 0) atomicAdd(&pooled[curg * D + j], acc);
}

// ---------------------------------------------------------------------------
// Classifier with fused per-graph counts (binary search on sorted batch).
__global__ void cls_kernel(const float* __restrict__ pooled,
                           const int* __restrict__ batch,
                           const float* __restrict__ Wcls,
                           const float* __restrict__ bcls,
                           float* __restrict__ out, int N) {
  int tid = blockIdx.x * blockDim.x + threadIdx.x;
  if (tid >= NGRAPH * NCLS) return;
  int g = tid / NCLS, c = tid % NCLS;
  int lo = 0, hi = N;
  while (lo < hi) { int m = (lo + hi) >> 1; if (batch[m] < g) lo = m + 1; else hi = m; }
  int start = lo;
  lo = 0; hi = N;
  while (lo < hi) { int m = (lo + hi) >> 1; if (batch[m] <= g) lo = m + 1; else hi = m; }
  float inv = 1.f / fmaxf((float)(lo - start), 1.f);
  float acc = bcls[c];
#pragma unroll 8
  for (int k = 0; k < D; k++) acc += pooled[g * D + k] * inv * Wcls[k * NCLS + c];
  out[g * NCLS + c] = acc;
}

// ---------------------------------------------------------------------------
extern "C" void kernel_launch(void* const* d_in, const int* in_sizes, int n_in,
                              void* d_out, int out_size, void* d_ws, size_t ws_size,
                              hipStream_t stream) {
  const float* x      = (const float*)d_in[0];
  const int*   ei     = (const int*)d_in[1];
  const int*   batch  = (const int*)d_in[2];
  const float* W_rel  = (const float*)d_in[3];
  const float* b_rel  = (const float*)d_in[4];
  const float* W_root = (const float*)d_in[5];
  const float* gamma  = (const float*)d_in[6];
  const float* beta   = (const float*)d_in[7];
  const float* W_cls  = (const float*)d_in[8];
  const float* b_cls  = (const float*)d_in[9];
  float* out = (float*)d_out;

  int E = in_sizes[1] / 2;
  int N = in_sizes[2];
  size_t nd = (size_t)N * D;
  int nbuck = (N + BUCK_SZ - 1) / BUCK_SZ;  // 196 for N=100k (<=256)
  int capB = ((2 * E / nbuck) + 511) & ~511;
  if (capB < 1024) capB = 1024;
  float fN = (float)N;

  // Workspace layout.
  float* bufA    = (float*)d_ws;                 // N*D: fp32 h (layer 2 only)
  float* bufB    = bufA + nd;                    // N*D: msg
  ushort* xbf    = (ushort*)(bufB + nd);         // N*D bf16 x/h chain
  float* stats3  = (float*)(xbf + nd);           // 3 * 2*D  -- zeroed
  float* pooled  = stats3 + 3 * 2 * D;           // NGRAPH*D -- zeroed
  int* gcnt      = (int*)(pooled + NGRAPH * D);  // nbuck -- zeroed
  ushort* wfrag  = (ushort*)(gcnt + ((nbuck + 3) & ~3));  // 3*16384 ushorts
  int* bstart    = (int*)(wfrag + 3 * 16384);    // nbuck+1
  int* row_start = bstart + nbuck + 1;           // N+1
  int* csr_src   = row_start + N + 1;            // E
  int* pk        = csr_src + E;                  // nbuck*capB

  size_t zero_bytes = (size_t)(3 * 2 * D + NGRAPH * D) * 4 +
                      (size_t)nbuck * 4;
  hipMemsetAsync(stats3, 0, zero_bytes, stream);

  // ---- CSR build + weight/x prep (once) ----
  bucket_scatter_kernel<<<(E + EPB - 1) / EPB, 256, 0, stream>>>(
      ei, gcnt, pk, E, capB, nbuck);
  bucket_scan_kernel<<<1, 256, 0, stream>>>(gcnt, bstart, row_start, nbuck, N, capB);
  bucket_place_kernel<<<nbuck, 256, 0, stream>>>(pk, gcnt, bstart, row_start,
                                                 csr_src, N, capB);
  wsplit_kernel<<<3, 256, 0, stream>>>(W_rel, W_root, wfrag);
  xprep_kernel<<<(int)((nd / 8 + 255) / 256), 256, 0, stream>>>(x, xbf, (int)nd);

  // ---- Layers (no bn_finalize: scale/shift computed inline from stats) ----
  const int MM_BLOCKS = 512;
  const int MM_WAVES = MM_BLOCKS * 4;
  int ntiles = (N + 15) / 16;
  for (int l = 0; l < 3; l++) {
    int apply = (l > 0) ? 1 : 0;
    int wbf = (l < 2) ? 1 : 0;
    int wh = (l == 2) ? 1 : 0;
    const float* st_prev = stats3 + (l > 0 ? (l - 1) * 2 * D : 0);
    const float* gm_prev = gamma + (l > 0 ? (l - 1) * D : 0);
    const float* bt_prev = beta + (l > 0 ? (l - 1) * D : 0);
    float* st_cur = stats3 + l * 2 * D;

    gather_kernel<<<(N + 3) / 4, 256, 0, stream>>>(
        xbf, csr_src, row_start, st_prev, gm_prev, bt_prev, fN, apply,
        bufB, N);

    mm_mfma_kernel<<<MM_BLOCKS, 256, 0, stream>>>(
        bufB, x, xbf, wfrag + l * 16384, b_rel + l * D,
        st_prev, gm_prev, bt_prev, fN, apply,
        bufA, xbf /* in-place bf16 h chain */, wh, wbf, st_cur,
        N, ntiles, MM_WAVES);
  }

  norm_relu_pool_kernel<<<(N + 255) / 256, 256, 0, stream>>>(
      bufA, stats3 + 2 * 2 * D, gamma + 2 * D, beta + 2 * D, fN, batch,
      pooled, N);
  cls_kernel<<<(NGRAPH * NCLS + 255) / 256, 256, 0, stream>>>(
      pooled, batch, W_cls, b_cls, out, N);
}

// Round 16
// 377.759 us; speedup vs baseline: 1.1292x; 1.1292x over previous
//
#include <hip/hip_runtime.h>

#define D 64
#define NGRAPH 128
#define NCLS 10
#define BN_EPS 1e-5f
#define BUCK_SZ 512   // dsts per bucket (2^9)
#define EPB 8192      // edges per block in pass 1

typedef __attribute__((ext_vector_type(8))) __bf16 bf16x8;
typedef __attribute__((ext_vector_type(4))) float floatx4;

union BF8 { bf16x8 v; ushort u[8]; };

// fp32 -> bf16 round-to-nearest-even (bits).
__device__ __forceinline__ unsigned f2bf_rne(float f) {
  unsigned u = __float_as_uint(f);
  return (u + 0x7FFFu + ((u >> 16) & 1u)) >> 16;
}
__device__ __forceinline__ unsigned pack2bf(float a, float b) {
  return f2bf_rne(a) | (f2bf_rne(b) << 16);
}
// Unpack 4 packed bf16 (uint2) -> float4.
__device__ __forceinline__ float4 bf4_to_f4(uint2 u) {
  float4 r;
  r.x = __uint_as_float(u.x << 16);
  r.y = __uint_as_float(u.x & 0xFFFF0000u);
  r.z = __uint_as_float(u.y << 16);
  r.w = __uint_as_float(u.y & 0xFFFF0000u);
  return r;
}

// BN scale/shift for feature f from raw stats (sum, sumsq).
__device__ __forceinline__ void bn_sc_sh(
    const float* __restrict__ stats, const float* __restrict__ gamma,
    const float* __restrict__ beta, float fN, int f, float* sc, float* sh) {
  float mean = stats[f] / fN;
  float var = stats[D + f] / fN - mean * mean;
  float s = gamma[f] * rsqrtf(var + BN_EPS);
  *sc = s;
  *sh = beta[f] - mean * s;
}

// Split 8 fp32 into bf16 hi (truncation) + bf16 lo (residual, truncated).
__device__ __forceinline__ void split8(float4 a, float4 b,
                                       bf16x8* hi, bf16x8* lo) {
  float f[8] = {a.x, a.y, a.z, a.w, b.x, b.y, b.z, b.w};
  BF8 H, L;
#pragma unroll
  for (int t = 0; t < 8; t++) {
    unsigned u = __float_as_uint(f[t]);
    H.u[t] = (ushort)(u >> 16);
    float hf = __uint_as_float(u & 0xFFFF0000u);
    float lf = f[t] - hf;
    L.u[t] = (ushort)(__float_as_uint(lf) >> 16);
  }
  *hi = H.v;
  *lo = L.v;
}

// ===========================================================================
// CSR build pass 1: block-aggregated bucket sort of edges.
// ===========================================================================
__global__ __launch_bounds__(256) void bucket_scatter_kernel(
    const int* __restrict__ ei, int* __restrict__ gcnt, int* __restrict__ pk,
    int E, int capB, int nbuck) {
  __shared__ int hist[256];
  __shared__ int base[256];
  int t = threadIdx.x;
  int e0 = blockIdx.x * EPB;
  int e1 = min(e0 + EPB, E);
  hist[t] = 0;
  __syncthreads();
  for (int e = e0 + t; e < e1; e += 256)
    atomicAdd(&hist[ei[E + e] >> 9], 1);
  __syncthreads();
  int h = hist[t];
  if (t < nbuck && h > 0) base[t] = atomicAdd(&gcnt[t], h);
  hist[t] = 0;  // reuse as per-bucket cursor
  __syncthreads();
  for (int e = e0 + t; e < e1; e += 256) {
    int s = ei[e];
    int d = ei[E + e];
    int b = d >> 9;
    int pos = base[b] + atomicAdd(&hist[b], 1);
    if (pos < capB) pk[(size_t)b * capB + pos] = (s << 9) | (d & (BUCK_SZ - 1));
  }
}

// Exclusive scan of per-bucket totals (nbuck <= 256); row_start[N] = total.
__global__ void bucket_scan_kernel(const int* __restrict__ gcnt,
                                   int* __restrict__ bstart,
                                   int* __restrict__ row_start,
                                   int nbuck, int N, int capB) {
  __shared__ int s[256];
  int t = threadIdx.x;
  int v = (t < nbuck) ? min(gcnt[t], capB) : 0;
  s[t] = v;
  __syncthreads();
  for (int off = 1; off < 256; off <<= 1) {
    int add = (t >= off) ? s[t - off] : 0;
    __syncthreads();
    s[t] += add;
    __syncthreads();
  }
  if (t < nbuck) bstart[t] = s[t] - v;
  if (t == 0) {
    bstart[nbuck] = s[255];
    row_start[N] = s[255];
  }
}

// Pass 2: one block per bucket: LDS histogram, scan, place.
__global__ __launch_bounds__(256) void bucket_place_kernel(
    const int* __restrict__ pk, const int* __restrict__ gcnt,
    const int* __restrict__ bstart, int* __restrict__ row_start,
    int* __restrict__ csr_src, int N, int capB) {
  __shared__ int hist[BUCK_SZ];
  __shared__ int scn[256];
  __shared__ int cur[BUCK_SZ];
  int b = blockIdx.x;
  int t = threadIdx.x;
  hist[t] = 0;
  hist[t + 256] = 0;
  int cnt = min(gcnt[b], capB);
  const int* seg = pk + (size_t)b * capB;
  __syncthreads();
  for (int e = t; e < cnt; e += 256)
    atomicAdd(&hist[seg[e] & (BUCK_SZ - 1)], 1);
  __syncthreads();
  scn[t] = hist[2 * t] + hist[2 * t + 1];
  __syncthreads();
  for (int off = 1; off < 256; off <<= 1) {
    int add = (t >= off) ? scn[t - off] : 0;
    __syncthreads();
    scn[t] += add;
    __syncthreads();
  }
  int base = bstart[b];
  int ex = (t == 0) ? 0 : scn[t - 1];
  int c0 = base + ex;
  int c1 = c0 + hist[2 * t];
  cur[2 * t] = c0;
  cur[2 * t + 1] = c1;
  int dst0 = b * BUCK_SZ + 2 * t;
  if (dst0 < N) row_start[dst0] = c0;
  if (dst0 + 1 < N) row_start[dst0 + 1] = c1;
  __syncthreads();
  for (int e = t; e < cnt; e += 256) {
    int p = seg[e];
    int slot = atomicAdd(&cur[p & (BUCK_SZ - 1)], 1);
    csr_src[slot] = p >> 9;
  }
}

// ===========================================================================
// Weight split+swizzle prep (once).
// ===========================================================================
__global__ __launch_bounds__(256) void wsplit_kernel(
    const float* __restrict__ Wrel, const float* __restrict__ Wroot,
    ushort* __restrict__ wfrag) {
  int l = blockIdx.x;  // 0..2
  const float* Wr = Wrel + l * 4096;
  const float* Wo = Wroot + l * 4096;
  ushort* base = wfrag + l * 16384;
  for (int slot = threadIdx.x; slot < 1024; slot += 256) {
    int kt = slot >> 8, nt = (slot >> 6) & 3, lane = slot & 63;
    int quad = lane >> 4, c = lane & 15;
    ushort* ph = base + (((kt * 4 + nt) * 2 + 0) * 64 + lane) * 8;
    ushort* pl = base + (((kt * 4 + nt) * 2 + 1) * 64 + lane) * 8;
#pragma unroll
    for (int j = 0; j < 8; j++) {
      int k = kt * 32 + quad * 8 + j;
      int n = nt * 16 + c;
      float w = (k < 64) ? Wr[k * 64 + n] : Wo[(k - 64) * 64 + n];
      unsigned u = __float_as_uint(w);
      ph[j] = (ushort)(u >> 16);
      float lf = w - __uint_as_float(u & 0xFFFF0000u);
      pl[j] = (ushort)(__float_as_uint(lf) >> 16);
    }
  }
}

// ===========================================================================
// x -> packed bf16 (RNE), once per call. 8 elements/thread.
// ===========================================================================
__global__ __launch_bounds__(256) void xprep_kernel(
    const float* __restrict__ x, ushort* __restrict__ xbf, int n) {
  int base = (blockIdx.x * 256 + threadIdx.x) * 8;
  if (base >= n) return;
  float4 a = *(const float4*)(x + base);
  float4 b = *(const float4*)(x + base + 4);
  uint4 o;
  o.x = pack2bf(a.x, a.y);
  o.y = pack2bf(a.z, a.w);
  o.z = pack2bf(b.x, b.y);
  o.w = pack2bf(b.z, b.w);
  *(uint4*)(xbf + base) = o;
}

// ===========================================================================
// Gather v3 (R12/R14 best-measured form): one wave per dst row, block = 4
// rows. ALL row indices preloaded in ONE coalesced load; value addresses via
// __shfl; 4 independent 8B bf16 loads per 16-edge pass (clamped index +
// mask-multiply). Cross-quad shfl reduce; quad 0 writes the fp32 msg row.
// BN scale/shift computed INLINE from prev layer's raw stats (apply=1).
// ===========================================================================
__global__ __launch_bounds__(256) void gather_kernel(
    const ushort* __restrict__ xbf, const int* __restrict__ csr_src,
    const int* __restrict__ row_start, const float* __restrict__ stats_prev,
    const float* __restrict__ gamma, const float* __restrict__ beta,
    float fN, int apply, float* __restrict__ msg, int N) {
  int i = blockIdx.x * 4 + (threadIdx.x >> 6);
  int lane = threadIdx.x & 63;
  int q = lane >> 4;         // edge sub-slot 0..3
  int f = (lane & 15) << 2;  // feature quad base
  if (i >= N) return;
  int e0 = row_start[i], e1 = row_start[i + 1];
  int cnt = e1 - e0;
  int myidx = csr_src[e0 + lane];  // coalesced; overread lands in pk (ours)
  float4 acc = {0.f, 0.f, 0.f, 0.f};
  float4 sc, sh;
  if (apply) {
    bn_sc_sh(stats_prev, gamma, beta, fN, f + 0, &sc.x, &sh.x);
    bn_sc_sh(stats_prev, gamma, beta, fN, f + 1, &sc.y, &sh.y);
    bn_sc_sh(stats_prev, gamma, beta, fN, f + 2, &sc.z, &sh.z);
    bn_sc_sh(stats_prev, gamma, beta, fN, f + 3, &sc.w, &sh.w);
  }

  int cnt64 = min(cnt, 64);
  for (int base = 0; base < cnt64; base += 16) {
    int j0 = base + q;  // this quad's 4 edges: j0, j0+4, j0+8, j0+12
    int s0 = __shfl(myidx, j0);
    int s1 = __shfl(myidx, j0 + 4);
    int s2 = __shfl(myidx, j0 + 8);
    int s3 = __shfl(myidx, j0 + 12);
    float m0 = (j0 < cnt) ? 1.f : 0.f;
    float m1 = (j0 + 4 < cnt) ? 1.f : 0.f;
    float m2 = (j0 + 8 < cnt) ? 1.f : 0.f;
    float m3 = (j0 + 12 < cnt) ? 1.f : 0.f;
    s0 = (j0 < cnt) ? s0 : 0;        // clamp address: no OOB deref
    s1 = (j0 + 4 < cnt) ? s1 : 0;
    s2 = (j0 + 8 < cnt) ? s2 : 0;
    s3 = (j0 + 12 < cnt) ? s3 : 0;
    float4 v0 = bf4_to_f4(*(const uint2*)(xbf + (size_t)s0 * D + f));
    float4 v1 = bf4_to_f4(*(const uint2*)(xbf + (size_t)s1 * D + f));
    float4 v2 = bf4_to_f4(*(const uint2*)(xbf + (size_t)s2 * D + f));
    float4 v3 = bf4_to_f4(*(const uint2*)(xbf + (size_t)s3 * D + f));
    if (apply) {
      acc.x += m0 * fmaxf(v0.x * sc.x + sh.x, 0.f) + m1 * fmaxf(v1.x * sc.x + sh.x, 0.f)
             + m2 * fmaxf(v2.x * sc.x + sh.x, 0.f) + m3 * fmaxf(v3.x * sc.x + sh.x, 0.f);
      acc.y += m0 * fmaxf(v0.y * sc.y + sh.y, 0.f) + m1 * fmaxf(v1.y * sc.y + sh.y, 0.f)
             + m2 * fmaxf(v2.y * sc.y + sh.y, 0.f) + m3 * fmaxf(v3.y * sc.y + sh.y, 0.f);
      acc.z += m0 * fmaxf(v0.z * sc.z + sh.z, 0.f) + m1 * fmaxf(v1.z * sc.z + sh.z, 0.f)
             + m2 * fmaxf(v2.z * sc.z + sh.z, 0.f) + m3 * fmaxf(v3.z * sc.z + sh.z, 0.f);
      acc.w += m0 * fmaxf(v0.w * sc.w + sh.w, 0.f) + m1 * fmaxf(v1.w * sc.w + sh.w, 0.f)
             + m2 * fmaxf(v2.w * sc.w + sh.w, 0.f) + m3 * fmaxf(v3.w * sc.w + sh.w, 0.f);
    } else {
      acc.x += m0 * v0.x + m1 * v1.x + m2 * v2.x + m3 * v3.x;
      acc.y += m0 * v0.y + m1 * v1.y + m2 * v2.y + m3 * v3.y;
      acc.z += m0 * v0.z + m1 * v1.z + m2 * v2.z + m3 * v3.z;
      acc.w += m0 * v0.w + m1 * v1.w + m2 * v2.w + m3 * v3.w;
    }
  }

  // Rare tail: rows with degree > 64.
  for (int e = e0 + 64 + q; e < e1; e += 4) {
    float4 v = bf4_to_f4(*(const uint2*)(xbf + (size_t)csr_src[e] * D + f));
    if (apply) {
      acc.x += fmaxf(v.x * sc.x + sh.x, 0.f);
      acc.y += fmaxf(v.y * sc.y + sh.y, 0.f);
      acc.z += fmaxf(v.z * sc.z + sh.z, 0.f);
      acc.w += fmaxf(v.w * sc.w + sh.w, 0.f);
    } else {
      acc.x += v.x; acc.y += v.y; acc.z += v.z; acc.w += v.w;
    }
  }

  acc.x += __shfl_xor(acc.x, 16); acc.x += __shfl_xor(acc.x, 32);
  acc.y += __shfl_xor(acc.y, 16); acc.y += __shfl_xor(acc.y, 32);
  acc.z += __shfl_xor(acc.z, 16); acc.z += __shfl_xor(acc.z, 32);
  acc.w += __shfl_xor(acc.w, 16); acc.w += __shfl_xor(acc.w, 32);
  if (q == 0) *(float4*)(msg + (size_t)i * D + f) = acc;
}

// ===========================================================================
// mm via MFMA split-bf16. Root-term input: fp32 x (apply=0) or bf16 hbf +
// inline BN/ReLU from prev stats (apply=1; in-place tile-local). Outputs:
// hbf (wbf=1) and/or fp32 h (wh=1). BN stats of h accumulated into
// stats_cur (per-layer buffer, pre-zeroed).
// ===========================================================================
__global__ __launch_bounds__(256, 1) void mm_mfma_kernel(
    const float* msg, const float* xf32, const ushort* xbfin,
    const ushort* __restrict__ wfrag, const float* __restrict__ brel,
    const float* __restrict__ stats_prev, const float* __restrict__ gamma,
    const float* __restrict__ beta, float fN, int apply,
    float* h, ushort* hbf, int wh, int wbf, float* __restrict__ stats_cur,
    int N, int ntiles, int nwaves) {
  __shared__ float ssum[4][64];
  __shared__ float ssq[4][64];
  int tid = threadIdx.x;
  int lane = tid & 63;
  int wvid = tid >> 6;
  int wv = (blockIdx.x * 256 + tid) >> 6;
  int quad = lane >> 4;
  int lo4 = lane & 15;

  bf16x8 bf[4][4][2];
#pragma unroll
  for (int kt = 0; kt < 4; kt++)
#pragma unroll
    for (int nt = 0; nt < 4; nt++)
#pragma unroll
      for (int s = 0; s < 2; s++)
        bf[kt][nt][s] =
            *(const bf16x8*)(wfrag + (((kt * 4 + nt) * 2 + s) * 64 + lane) * 8);

  float bias[4];
#pragma unroll
  for (int nt = 0; nt < 4; nt++) bias[nt] = brel[nt * 16 + lo4];

  float scx[2][8], shx[2][8];
  if (apply) {
#pragma unroll
    for (int hh = 0; hh < 2; hh++)
#pragma unroll
      for (int jj = 0; jj < 8; jj++) {
        int f = hh * 32 + quad * 8 + jj;
        bn_sc_sh(stats_prev, gamma, beta, fN, f, &scx[hh][jj], &shx[hh][jj]);
      }
  }

  float psum[4] = {0.f, 0.f, 0.f, 0.f};
  float psq[4] = {0.f, 0.f, 0.f, 0.f};

  for (int t = wv; t < ntiles; t += nwaves) {
    int i0 = t * 16;
    int row = i0 + lo4;
    if (row >= N) row = N - 1;
    bf16x8 ahi[4], alo[4];
#pragma unroll
    for (int kt = 0; kt < 4; kt++) {
      float4 a, b;
      if (kt < 2) {
        const float* p = msg + (size_t)row * D + (kt & 1) * 32 + quad * 8;
        a = *(const float4*)p;
        b = *(const float4*)(p + 4);
      } else if (apply) {
        const ushort* p = xbfin + (size_t)row * D + (kt & 1) * 32 + quad * 8;
        uint4 u = *(const uint4*)p;
        uint2 ulo = {u.x, u.y}, uhi = {u.z, u.w};
        a = bf4_to_f4(ulo);
        b = bf4_to_f4(uhi);
        int hh = kt - 2;
        a.x = fmaxf(a.x * scx[hh][0] + shx[hh][0], 0.f);
        a.y = fmaxf(a.y * scx[hh][1] + shx[hh][1], 0.f);
        a.z = fmaxf(a.z * scx[hh][2] + shx[hh][2], 0.f);
        a.w = fmaxf(a.w * scx[hh][3] + shx[hh][3], 0.f);
        b.x = fmaxf(b.x * scx[hh][4] + shx[hh][4], 0.f);
        b.y = fmaxf(b.y * scx[hh][5] + shx[hh][5], 0.f);
        b.z = fmaxf(b.z * scx[hh][6] + shx[hh][6], 0.f);
        b.w = fmaxf(b.w * scx[hh][7] + shx[hh][7], 0.f);
      } else {
        const float* p = xf32 + (size_t)row * D + (kt & 1) * 32 + quad * 8;
        a = *(const float4*)p;
        b = *(const float4*)(p + 4);
      }
      split8(a, b, &ahi[kt], &alo[kt]);
    }
#pragma unroll
    for (int nt = 0; nt < 4; nt++) {
      floatx4 acc = {bias[nt], bias[nt], bias[nt], bias[nt]};
#pragma unroll
      for (int kt = 0; kt < 4; kt++) {
        acc = __builtin_amdgcn_mfma_f32_16x16x32_bf16(ahi[kt], bf[kt][nt][0],
                                                      acc, 0, 0, 0);
        acc = __builtin_amdgcn_mfma_f32_16x16x32_bf16(ahi[kt], bf[kt][nt][1],
                                                      acc, 0, 0, 0);
        acc = __builtin_amdgcn_mfma_f32_16x16x32_bf16(alo[kt], bf[kt][nt][0],
                                                      acc, 0, 0, 0);
      }
#pragma unroll
      for (int r = 0; r < 4; r++) {
        int grow = i0 + quad * 4 + r;
        if (grow < N) {
          float v = acc[r];
          size_t idx = (size_t)grow * D + nt * 16 + lo4;
          if (wh) h[idx] = v;
          if (wbf) hbf[idx] = (ushort)f2bf_rne(v);
          psum[nt] += v;
          psq[nt] += v * v;
        }
      }
    }
  }

#pragma unroll
  for (int nt = 0; nt < 4; nt++) {
    float s = psum[nt], q = psq[nt];
    s += __shfl_xor(s, 16); s += __shfl_xor(s, 32);
    q += __shfl_xor(q, 16); q += __shfl_xor(q, 32);
    if (lane < 16) { ssum[wvid][nt * 16 + lane] = s; ssq[wvid][nt * 16 + lane] = q; }
  }
  __syncthreads();
  if (tid < 64) {
    atomicAdd(&stats_cur[tid],
              ssum[0][tid] + ssum[1][tid] + ssum[2][tid] + ssum[3][tid]);
  } else if (tid < 128) {
    int c = tid - 64;
    atomicAdd(&stats_cur[D + c],
              ssq[0][c] + ssq[1][c] + ssq[2][c] + ssq[3][c]);
  }
}

// ---------------------------------------------------------------------------
// Final layer: inline BN + ReLU fused with graph mean-pool (batch sorted).
__global__ __launch_bounds__(256) void norm_relu_pool_kernel(
    const float* __restrict__ h, const float* __restrict__ stats,
    const float* __restrict__ gamma, const float* __restrict__ beta,
    float fN, const int* __restrict__ batch, float* __restrict__ pooled,
    int N) {
  int j = threadIdx.x & 63;
  int q = threadIdx.x >> 6;
  int i0 = blockIdx.x * 256;
  float sc, sh;
  bn_sc_sh(stats, gamma, beta, fN, j, &sc, &sh);
  int curg = -1;
  float acc = 0.f;
  for (int r = q; r < 256; r += 4) {
    int i = i0 + r;
    if (i >= N) break;
    int b = batch[i];
    float v = fmaxf(h[(size_t)i * D + j] * sc + sh, 0.f);
    if (b != curg) {
      if (curg >= 0) atomicAdd(&pooled[curg * D + j], acc);
      curg = b;
      acc = v;
    } else {
      acc += v;
    }
  }
  if (curg >= 0) atomicAdd(&pooled[curg * D + j], acc);
}

// ---------------------------------------------------------------------------
// Classifier with fused per-graph counts (binary search on sorted batch).
__global__ void cls_kernel(const float* __restrict__ pooled,
                           const int* __restrict__ batch,
                           const float* __restrict__ Wcls,
                           const float* __restrict__ bcls,
                           float* __restrict__ out, int N) {
  int tid = blockIdx.x * blockDim.x + threadIdx.x;
  if (tid >= NGRAPH * NCLS) return;
  int g = tid / NCLS, c = tid % NCLS;
  int lo = 0, hi = N;
  while (lo < hi) { int m = (lo + hi) >> 1; if (batch[m] < g) lo = m + 1; else hi = m; }
  int start = lo;
  lo = 0; hi = N;
  while (lo < hi) { int m = (lo + hi) >> 1; if (batch[m] <= g) lo = m + 1; else hi = m; }
  float inv = 1.f / fmaxf((float)(lo - start), 1.f);
  float acc = bcls[c];
#pragma unroll 8
  for (int k = 0; k < D; k++) acc += pooled[g * D + k] * inv * Wcls[k * NCLS + c];
  out[g * NCLS + c] = acc;
}

// ---------------------------------------------------------------------------
extern "C" void kernel_launch(void* const* d_in, const int* in_sizes, int n_in,
                              void* d_out, int out_size, void* d_ws, size_t ws_size,
                              hipStream_t stream) {
  const float* x      = (const float*)d_in[0];
  const int*   ei     = (const int*)d_in[1];
  const int*   batch  = (const int*)d_in[2];
  const float* W_rel  = (const float*)d_in[3];
  const float* b_rel  = (const float*)d_in[4];
  const float* W_root = (const float*)d_in[5];
  const float* gamma  = (const float*)d_in[6];
  const float* beta   = (const float*)d_in[7];
  const float* W_cls  = (const float*)d_in[8];
  const float* b_cls  = (const float*)d_in[9];
  float* out = (float*)d_out;

  int E = in_sizes[1] / 2;
  int N = in_sizes[2];
  size_t nd = (size_t)N * D;
  int nbuck = (N + BUCK_SZ - 1) / BUCK_SZ;  // 196 for N=100k (<=256)
  int capB = ((2 * E / nbuck) + 511) & ~511;
  if (capB < 1024) capB = 1024;
  float fN = (float)N;

  // Workspace layout.
  float* bufA    = (float*)d_ws;                 // N*D: fp32 h (layer 2 only)
  float* bufB    = bufA + nd;                    // N*D: msg
  ushort* xbf    = (ushort*)(bufB + nd);         // N*D bf16 x/h chain
  float* stats3  = (float*)(xbf + nd);           // 3 * 2*D  -- zeroed
  float* pooled  = stats3 + 3 * 2 * D;           // NGRAPH*D -- zeroed
  int* gcnt      = (int*)(pooled + NGRAPH * D);  // nbuck -- zeroed
  ushort* wfrag  = (ushort*)(gcnt + ((nbuck + 3) & ~3));  // 3*16384 ushorts
  int* bstart    = (int*)(wfrag + 3 * 16384);    // nbuck+1
  int* row_start = bstart + nbuck + 1;           // N+1
  int* csr_src   = row_start + N + 1;            // E
  int* pk        = csr_src + E;                  // nbuck*capB

  size_t zero_bytes = (size_t)(3 * 2 * D + NGRAPH * D) * 4 +
                      (size_t)nbuck * 4;
  hipMemsetAsync(stats3, 0, zero_bytes, stream);

  // ---- CSR build + weight/x prep (once) ----
  bucket_scatter_kernel<<<(E + EPB - 1) / EPB, 256, 0, stream>>>(
      ei, gcnt, pk, E, capB, nbuck);
  bucket_scan_kernel<<<1, 256, 0, stream>>>(gcnt, bstart, row_start, nbuck, N, capB);
  bucket_place_kernel<<<nbuck, 256, 0, stream>>>(pk, gcnt, bstart, row_start,
                                                 csr_src, N, capB);
  wsplit_kernel<<<3, 256, 0, stream>>>(W_rel, W_root, wfrag);
  xprep_kernel<<<(int)((nd / 8 + 255) / 256), 256, 0, stream>>>(x, xbf, (int)nd);

  // ---- Layers (no bn_finalize: scale/shift computed inline from stats) ----
  const int MM_BLOCKS = 512;
  const int MM_WAVES = MM_BLOCKS * 4;
  int ntiles = (N + 15) / 16;
  for (int l = 0; l < 3; l++) {
    int apply = (l > 0) ? 1 : 0;
    int wbf = (l < 2) ? 1 : 0;
    int wh = (l == 2) ? 1 : 0;
    const float* st_prev = stats3 + (l > 0 ? (l - 1) * 2 * D : 0);
    const float* gm_prev = gamma + (l > 0 ? (l - 1) * D : 0);
    const float* bt_prev = beta + (l > 0 ? (l - 1) * D : 0);
    float* st_cur = stats3 + l * 2 * D;

    gather_kernel<<<(N + 3) / 4, 256, 0, stream>>>(
        xbf, csr_src, row_start, st_prev, gm_prev, bt_prev, fN, apply,
        bufB, N);

    mm_mfma_kernel<<<MM_BLOCKS, 256, 0, stream>>>(
        bufB, x, xbf, wfrag + l * 16384, b_rel + l * D,
        st_prev, gm_prev, bt_prev, fN, apply,
        bufA, xbf /* in-place bf16 h chain */, wh, wbf, st_cur,
        N, ntiles, MM_WAVES);
  }

  norm_relu_pool_kernel<<<(N + 255) / 256, 256, 0, stream>>>(
      bufA, stats3 + 2 * 2 * D, gamma + 2 * D, beta + 2 * D, fN, batch,
      pooled, N);
  cls_kernel<<<(NGRAPH * NCLS + 255) / 256, 256, 0, stream>>>(
      pooled, batch, W_cls, b_cls, out, N);
}

// Round 17
// 357.910 us; speedup vs baseline: 1.1919x; 1.0555x over previous
//
#include <hip/hip_runtime.h>

#define D 64
#define NGRAPH 128
#define NCLS 10
#define BN_EPS 1e-5f
#define BUCK_SZ 512   // dsts per bucket (2^9)
#define EPB 8192      // edges per block in pass 1

typedef __attribute__((ext_vector_type(8))) __bf16 bf16x8;
typedef __attribute__((ext_vector_type(4))) float floatx4;

union BF8 { bf16x8 v; ushort u[8]; };

// fp32 -> bf16 round-to-nearest-even (bits).
__device__ __forceinline__ unsigned f2bf_rne(float f) {
  unsigned u = __float_as_uint(f);
  return (u + 0x7FFFu + ((u >> 16) & 1u)) >> 16;
}
__device__ __forceinline__ unsigned pack2bf(float a, float b) {
  return f2bf_rne(a) | (f2bf_rne(b) << 16);
}
// Unpack 4 packed bf16 (uint2) -> float4.
__device__ __forceinline__ float4 bf4_to_f4(uint2 u) {
  float4 r;
  r.x = __uint_as_float(u.x << 16);
  r.y = __uint_as_float(u.x & 0xFFFF0000u);
  r.z = __uint_as_float(u.y << 16);
  r.w = __uint_as_float(u.y & 0xFFFF0000u);
  return r;
}

// BN scale/shift for feature f from raw stats (sum, sumsq).
// invN precomputed on HOST: avoids the ~12-instr fp32 divide sequence that
// made R16's gather VALU-bound (VALUBusy 90%).
__device__ __forceinline__ void bn_sc_sh(
    const float* __restrict__ stats, const float* __restrict__ gamma,
    const float* __restrict__ beta, float invN, int f, float* sc, float* sh) {
  float mean = stats[f] * invN;
  float var = stats[D + f] * invN - mean * mean;
  float s = gamma[f] * rsqrtf(var + BN_EPS);
  *sc = s;
  *sh = beta[f] - mean * s;
}

// Split 8 fp32 into bf16 hi (truncation) + bf16 lo (residual, truncated).
__device__ __forceinline__ void split8(float4 a, float4 b,
                                       bf16x8* hi, bf16x8* lo) {
  float f[8] = {a.x, a.y, a.z, a.w, b.x, b.y, b.z, b.w};
  BF8 H, L;
#pragma unroll
  for (int t = 0; t < 8; t++) {
    unsigned u = __float_as_uint(f[t]);
    H.u[t] = (ushort)(u >> 16);
    float hf = __uint_as_float(u & 0xFFFF0000u);
    float lf = f[t] - hf;
    L.u[t] = (ushort)(__float_as_uint(lf) >> 16);
  }
  *hi = H.v;
  *lo = L.v;
}

// ===========================================================================
// CSR build pass 1: block-aggregated bucket sort of edges.
// ===========================================================================
__global__ __launch_bounds__(256) void bucket_scatter_kernel(
    const int* __restrict__ ei, int* __restrict__ gcnt, int* __restrict__ pk,
    int E, int capB, int nbuck) {
  __shared__ int hist[256];
  __shared__ int base[256];
  int t = threadIdx.x;
  int e0 = blockIdx.x * EPB;
  int e1 = min(e0 + EPB, E);
  hist[t] = 0;
  __syncthreads();
  for (int e = e0 + t; e < e1; e += 256)
    atomicAdd(&hist[ei[E + e] >> 9], 1);
  __syncthreads();
  int h = hist[t];
  if (t < nbuck && h > 0) base[t] = atomicAdd(&gcnt[t], h);
  hist[t] = 0;  // reuse as per-bucket cursor
  __syncthreads();
  for (int e = e0 + t; e < e1; e += 256) {
    int s = ei[e];
    int d = ei[E + e];
    int b = d >> 9;
    int pos = base[b] + atomicAdd(&hist[b], 1);
    if (pos < capB) pk[(size_t)b * capB + pos] = (s << 9) | (d & (BUCK_SZ - 1));
  }
}

// Exclusive scan of per-bucket totals (nbuck <= 256); row_start[N] = total.
__global__ void bucket_scan_kernel(const int* __restrict__ gcnt,
                                   int* __restrict__ bstart,
                                   int* __restrict__ row_start,
                                   int nbuck, int N, int capB) {
  __shared__ int s[256];
  int t = threadIdx.x;
  int v = (t < nbuck) ? min(gcnt[t], capB) : 0;
  s[t] = v;
  __syncthreads();
  for (int off = 1; off < 256; off <<= 1) {
    int add = (t >= off) ? s[t - off] : 0;
    __syncthreads();
    s[t] += add;
    __syncthreads();
  }
  if (t < nbuck) bstart[t] = s[t] - v;
  if (t == 0) {
    bstart[nbuck] = s[255];
    row_start[N] = s[255];
  }
}

// Pass 2: one block per bucket: LDS histogram, scan, place.
__global__ __launch_bounds__(256) void bucket_place_kernel(
    const int* __restrict__ pk, const int* __restrict__ gcnt,
    const int* __restrict__ bstart, int* __restrict__ row_start,
    int* __restrict__ csr_src, int N, int capB) {
  __shared__ int hist[BUCK_SZ];
  __shared__ int scn[256];
  __shared__ int cur[BUCK_SZ];
  int b = blockIdx.x;
  int t = threadIdx.x;
  hist[t] = 0;
  hist[t + 256] = 0;
  int cnt = min(gcnt[b], capB);
  const int* seg = pk + (size_t)b * capB;
  __syncthreads();
  for (int e = t; e < cnt; e += 256)
    atomicAdd(&hist[seg[e] & (BUCK_SZ - 1)], 1);
  __syncthreads();
  scn[t] = hist[2 * t] + hist[2 * t + 1];
  __syncthreads();
  for (int off = 1; off < 256; off <<= 1) {
    int add = (t >= off) ? scn[t - off] : 0;
    __syncthreads();
    scn[t] += add;
    __syncthreads();
  }
  int base = bstart[b];
  int ex = (t == 0) ? 0 : scn[t - 1];
  int c0 = base + ex;
  int c1 = c0 + hist[2 * t];
  cur[2 * t] = c0;
  cur[2 * t + 1] = c1;
  int dst0 = b * BUCK_SZ + 2 * t;
  if (dst0 < N) row_start[dst0] = c0;
  if (dst0 + 1 < N) row_start[dst0 + 1] = c1;
  __syncthreads();
  for (int e = t; e < cnt; e += 256) {
    int p = seg[e];
    int slot = atomicAdd(&cur[p & (BUCK_SZ - 1)], 1);
    csr_src[slot] = p >> 9;
  }
}

// ===========================================================================
// Weight split+swizzle prep (once).
// ===========================================================================
__global__ __launch_bounds__(256) void wsplit_kernel(
    const float* __restrict__ Wrel, const float* __restrict__ Wroot,
    ushort* __restrict__ wfrag) {
  int l = blockIdx.x;  // 0..2
  const float* Wr = Wrel + l * 4096;
  const float* Wo = Wroot + l * 4096;
  ushort* base = wfrag + l * 16384;
  for (int slot = threadIdx.x; slot < 1024; slot += 256) {
    int kt = slot >> 8, nt = (slot >> 6) & 3, lane = slot & 63;
    int quad = lane >> 4, c = lane & 15;
    ushort* ph = base + (((kt * 4 + nt) * 2 + 0) * 64 + lane) * 8;
    ushort* pl = base + (((kt * 4 + nt) * 2 + 1) * 64 + lane) * 8;
#pragma unroll
    for (int j = 0; j < 8; j++) {
      int k = kt * 32 + quad * 8 + j;
      int n = nt * 16 + c;
      float w = (k < 64) ? Wr[k * 64 + n] : Wo[(k - 64) * 64 + n];
      unsigned u = __float_as_uint(w);
      ph[j] = (ushort)(u >> 16);
      float lf = w - __uint_as_float(u & 0xFFFF0000u);
      pl[j] = (ushort)(__float_as_uint(lf) >> 16);
    }
  }
}

// ===========================================================================
// x -> packed bf16 (RNE), once per call. 8 elements/thread.
// ===========================================================================
__global__ __launch_bounds__(256) void xprep_kernel(
    const float* __restrict__ x, ushort* __restrict__ xbf, int n) {
  int base = (blockIdx.x * 256 + threadIdx.x) * 8;
  if (base >= n) return;
  float4 a = *(const float4*)(x + base);
  float4 b = *(const float4*)(x + base + 4);
  uint4 o;
  o.x = pack2bf(a.x, a.y);
  o.y = pack2bf(a.z, a.w);
  o.z = pack2bf(b.x, b.y);
  o.w = pack2bf(b.z, b.w);
  *(uint4*)(xbf + base) = o;
}

// ===========================================================================
// Gather v3 (best-measured form): one wave per dst row, block = 4 rows.
// ALL row indices preloaded in ONE coalesced load; value addresses via
// __shfl; 4 independent 8B bf16 loads per 16-edge pass (clamped index +
// mask-multiply). Cross-quad shfl reduce; quad 0 writes the fp32 msg row.
// BN scale/shift inline from prev raw stats (cheap now: invN multiply).
// ===========================================================================
__global__ __launch_bounds__(256) void gather_kernel(
    const ushort* __restrict__ xbf, const int* __restrict__ csr_src,
    const int* __restrict__ row_start, const float* __restrict__ stats_prev,
    const float* __restrict__ gamma, const float* __restrict__ beta,
    float invN, int apply, float* __restrict__ msg, int N) {
  int i = blockIdx.x * 4 + (threadIdx.x >> 6);
  int lane = threadIdx.x & 63;
  int q = lane >> 4;         // edge sub-slot 0..3
  int f = (lane & 15) << 2;  // feature quad base
  if (i >= N) return;
  int e0 = row_start[i], e1 = row_start[i + 1];
  int cnt = e1 - e0;
  int myidx = csr_src[e0 + lane];  // coalesced; overread lands in pk (ours)
  float4 acc = {0.f, 0.f, 0.f, 0.f};
  float4 sc, sh;
  if (apply) {
    bn_sc_sh(stats_prev, gamma, beta, invN, f + 0, &sc.x, &sh.x);
    bn_sc_sh(stats_prev, gamma, beta, invN, f + 1, &sc.y, &sh.y);
    bn_sc_sh(stats_prev, gamma, beta, invN, f + 2, &sc.z, &sh.z);
    bn_sc_sh(stats_prev, gamma, beta, invN, f + 3, &sc.w, &sh.w);
  }

  int cnt64 = min(cnt, 64);
  for (int base = 0; base < cnt64; base += 16) {
    int j0 = base + q;  // this quad's 4 edges: j0, j0+4, j0+8, j0+12
    int s0 = __shfl(myidx, j0);
    int s1 = __shfl(myidx, j0 + 4);
    int s2 = __shfl(myidx, j0 + 8);
    int s3 = __shfl(myidx, j0 + 12);
    float m0 = (j0 < cnt) ? 1.f : 0.f;
    float m1 = (j0 + 4 < cnt) ? 1.f : 0.f;
    float m2 = (j0 + 8 < cnt) ? 1.f : 0.f;
    float m3 = (j0 + 12 < cnt) ? 1.f : 0.f;
    s0 = (j0 < cnt) ? s0 : 0;        // clamp address: no OOB deref
    s1 = (j0 + 4 < cnt) ? s1 : 0;
    s2 = (j0 + 8 < cnt) ? s2 : 0;
    s3 = (j0 + 12 < cnt) ? s3 : 0;
    float4 v0 = bf4_to_f4(*(const uint2*)(xbf + (size_t)s0 * D + f));
    float4 v1 = bf4_to_f4(*(const uint2*)(xbf + (size_t)s1 * D + f));
    float4 v2 = bf4_to_f4(*(const uint2*)(xbf + (size_t)s2 * D + f));
    float4 v3 = bf4_to_f4(*(const uint2*)(xbf + (size_t)s3 * D + f));
    if (apply) {
      acc.x += m0 * fmaxf(v0.x * sc.x + sh.x, 0.f) + m1 * fmaxf(v1.x * sc.x + sh.x, 0.f)
             + m2 * fmaxf(v2.x * sc.x + sh.x, 0.f) + m3 * fmaxf(v3.x * sc.x + sh.x, 0.f);
      acc.y += m0 * fmaxf(v0.y * sc.y + sh.y, 0.f) + m1 * fmaxf(v1.y * sc.y + sh.y, 0.f)
             + m2 * fmaxf(v2.y * sc.y + sh.y, 0.f) + m3 * fmaxf(v3.y * sc.y + sh.y, 0.f);
      acc.z += m0 * fmaxf(v0.z * sc.z + sh.z, 0.f) + m1 * fmaxf(v1.z * sc.z + sh.z, 0.f)
             + m2 * fmaxf(v2.z * sc.z + sh.z, 0.f) + m3 * fmaxf(v3.z * sc.z + sh.z, 0.f);
      acc.w += m0 * fmaxf(v0.w * sc.w + sh.w, 0.f) + m1 * fmaxf(v1.w * sc.w + sh.w, 0.f)
             + m2 * fmaxf(v2.w * sc.w + sh.w, 0.f) + m3 * fmaxf(v3.w * sc.w + sh.w, 0.f);
    } else {
      acc.x += m0 * v0.x + m1 * v1.x + m2 * v2.x + m3 * v3.x;
      acc.y += m0 * v0.y + m1 * v1.y + m2 * v2.y + m3 * v3.y;
      acc.z += m0 * v0.z + m1 * v1.z + m2 * v2.z + m3 * v3.z;
      acc.w += m0 * v0.w + m1 * v1.w + m2 * v2.w + m3 * v3.w;
    }
  }

  // Rare tail: rows with degree > 64.
  for (int e = e0 + 64 + q; e < e1; e += 4) {
    float4 v = bf4_to_f4(*(const uint2*)(xbf + (size_t)csr_src[e] * D + f));
    if (apply) {
      acc.x += fmaxf(v.x * sc.x + sh.x, 0.f);
      acc.y += fmaxf(v.y * sc.y + sh.y, 0.f);
      acc.z += fmaxf(v.z * sc.z + sh.z, 0.f);
      acc.w += fmaxf(v.w * sc.w + sh.w, 0.f);
    } else {
      acc.x += v.x; acc.y += v.y; acc.z += v.z; acc.w += v.w;
    }
  }

  acc.x += __shfl_xor(acc.x, 16); acc.x += __shfl_xor(acc.x, 32);
  acc.y += __shfl_xor(acc.y, 16); acc.y += __shfl_xor(acc.y, 32);
  acc.z += __shfl_xor(acc.z, 16); acc.z += __shfl_xor(acc.z, 32);
  acc.w += __shfl_xor(acc.w, 16); acc.w += __shfl_xor(acc.w, 32);
  if (q == 0) *(float4*)(msg + (size_t)i * D + f) = acc;
}

// ===========================================================================
// mm via MFMA split-bf16. Root-term input: fp32 x (apply=0) or bf16 hbf +
// inline BN/ReLU from prev stats (apply=1; in-place tile-local). Outputs:
// hbf (wbf=1) and/or fp32 h (wh=1). BN stats of h accumulated into
// stats_cur (per-layer buffer, pre-zeroed).
// ===========================================================================
__global__ __launch_bounds__(256, 1) void mm_mfma_kernel(
    const float* msg, const float* xf32, const ushort* xbfin,
    const ushort* __restrict__ wfrag, const float* __restrict__ brel,
    const float* __restrict__ stats_prev, const float* __restrict__ gamma,
    const float* __restrict__ beta, float invN, int apply,
    float* h, ushort* hbf, int wh, int wbf, float* __restrict__ stats_cur,
    int N, int ntiles, int nwaves) {
  __shared__ float ssum[4][64];
  __shared__ float ssq[4][64];
  int tid = threadIdx.x;
  int lane = tid & 63;
  int wvid = tid >> 6;
  int wv = (blockIdx.x * 256 + tid) >> 6;
  int quad = lane >> 4;
  int lo4 = lane & 15;

  bf16x8 bf[4][4][2];
#pragma unroll
  for (int kt = 0; kt < 4; kt++)
#pragma unroll
    for (int nt = 0; nt < 4; nt++)
#pragma unroll
      for (int s = 0; s < 2; s++)
        bf[kt][nt][s] =
            *(const bf16x8*)(wfrag + (((kt * 4 + nt) * 2 + s) * 64 + lane) * 8);

  float bias[4];
#pragma unroll
  for (int nt = 0; nt < 4; nt++) bias[nt] = brel[nt * 16 + lo4];

  float scx[2][8], shx[2][8];
  if (apply) {
#pragma unroll
    for (int hh = 0; hh < 2; hh++)
#pragma unroll
      for (int jj = 0; jj < 8; jj++) {
        int f = hh * 32 + quad * 8 + jj;
        bn_sc_sh(stats_prev, gamma, beta, invN, f, &scx[hh][jj], &shx[hh][jj]);
      }
  }

  float psum[4] = {0.f, 0.f, 0.f, 0.f};
  float psq[4] = {0.f, 0.f, 0.f, 0.f};

  for (int t = wv; t < ntiles; t += nwaves) {
    int i0 = t * 16;
    int row = i0 + lo4;
    if (row >= N) row = N - 1;
    bf16x8 ahi[4], alo[4];
#pragma unroll
    for (int kt = 0; kt < 4; kt++) {
      float4 a, b;
      if (kt < 2) {
        const float* p = msg + (size_t)row * D + (kt & 1) * 32 + quad * 8;
        a = *(const float4*)p;
        b = *(const float4*)(p + 4);
      } else if (apply) {
        const ushort* p = xbfin + (size_t)row * D + (kt & 1) * 32 + quad * 8;
        uint4 u = *(const uint4*)p;
        uint2 ulo = {u.x, u.y}, uhi = {u.z, u.w};
        a = bf4_to_f4(ulo);
        b = bf4_to_f4(uhi);
        int hh = kt - 2;
        a.x = fmaxf(a.x * scx[hh][0] + shx[hh][0], 0.f);
        a.y = fmaxf(a.y * scx[hh][1] + shx[hh][1], 0.f);
        a.z = fmaxf(a.z * scx[hh][2] + shx[hh][2], 0.f);
        a.w = fmaxf(a.w * scx[hh][3] + shx[hh][3], 0.f);
        b.x = fmaxf(b.x * scx[hh][4] + shx[hh][4], 0.f);
        b.y = fmaxf(b.y * scx[hh][5] + shx[hh][5], 0.f);
        b.z = fmaxf(b.z * scx[hh][6] + shx[hh][6], 0.f);
        b.w = fmaxf(b.w * scx[hh][7] + shx[hh][7], 0.f);
      } else {
        const float* p = xf32 + (size_t)row * D + (kt & 1) * 32 + quad * 8;
        a = *(const float4*)p;
        b = *(const float4*)(p + 4);
      }
      split8(a, b, &ahi[kt], &alo[kt]);
    }
#pragma unroll
    for (int nt = 0; nt < 4; nt++) {
      floatx4 acc = {bias[nt], bias[nt], bias[nt], bias[nt]};
#pragma unroll
      for (int kt = 0; kt < 4; kt++) {
        acc = __builtin_amdgcn_mfma_f32_16x16x32_bf16(ahi[kt], bf[kt][nt][0],
                                                      acc, 0, 0, 0);
        acc = __builtin_amdgcn_mfma_f32_16x16x32_bf16(ahi[kt], bf[kt][nt][1],
                                                      acc, 0, 0, 0);
        acc = __builtin_amdgcn_mfma_f32_16x16x32_bf16(alo[kt], bf[kt][nt][0],
                                                      acc, 0, 0, 0);
      }
#pragma unroll
      for (int r = 0; r < 4; r++) {
        int grow = i0 + quad * 4 + r;
        if (grow < N) {
          float v = acc[r];
          size_t idx = (size_t)grow * D + nt * 16 + lo4;
          if (wh) h[idx] = v;
          if (wbf) hbf[idx] = (ushort)f2bf_rne(v);
          psum[nt] += v;
          psq[nt] += v * v;
        }
      }
    }
  }

#pragma unroll
  for (int nt = 0; nt < 4; nt++) {
    float s = psum[nt], q = psq[nt];
    s += __shfl_xor(s, 16); s += __shfl_xor(s, 32);
    q += __shfl_xor(q, 16); q += __shfl_xor(q, 32);
    if (lane < 16) { ssum[wvid][nt * 16 + lane] = s; ssq[wvid][nt * 16 + lane] = q; }
  }
  __syncthreads();
  if (tid < 64) {
    atomicAdd(&stats_cur[tid],
              ssum[0][tid] + ssum[1][tid] + ssum[2][tid] + ssum[3][tid]);
  } else if (tid < 128) {
    int c = tid - 64;
    atomicAdd(&stats_cur[D + c],
              ssq[0][c] + ssq[1][c] + ssq[2][c] + ssq[3][c]);
  }
}

// ---------------------------------------------------------------------------
// Final layer: inline BN + ReLU fused with graph mean-pool (batch sorted).
__global__ __launch_bounds__(256) void norm_relu_pool_kernel(
    const float* __restrict__ h, const float* __restrict__ stats,
    const float* __restrict__ gamma, const float* __restrict__ beta,
    float invN, const int* __restrict__ batch, float* __restrict__ pooled,
    int N) {
  int j = threadIdx.x & 63;
  int q = threadIdx.x >> 6;
  int i0 = blockIdx.x * 256;
  float sc, sh;
  bn_sc_sh(stats, gamma, beta, invN, j, &sc, &sh);
  int curg = -1;
  float acc = 0.f;
  for (int r = q; r < 256; r += 4) {
    int i = i0 + r;
    if (i >= N) break;
    int b = batch[i];
    float v = fmaxf(h[(size_t)i * D + j] * sc + sh, 0.f);
    if (b != curg) {
      if (curg >= 0) atomicAdd(&pooled[curg * D + j], acc);
      curg = b;
      acc = v;
    } else {
      acc += v;
    }
  }
  if (curg >= 0) atomicAdd(&pooled[curg * D + j], acc);
}

// ---------------------------------------------------------------------------
// Classifier with fused per-graph counts (binary search on sorted batch).
__global__ void cls_kernel(const float* __restrict__ pooled,
                           const int* __restrict__ batch,
                           const float* __restrict__ Wcls,
                           const float* __restrict__ bcls,
                           float* __restrict__ out, int N) {
  int tid = blockIdx.x * blockDim.x + threadIdx.x;
  if (tid >= NGRAPH * NCLS) return;
  int g = tid / NCLS, c = tid % NCLS;
  int lo = 0, hi = N;
  while (lo < hi) { int m = (lo + hi) >> 1; if (batch[m] < g) lo = m + 1; else hi = m; }
  int start = lo;
  lo = 0; hi = N;
  while (lo < hi) { int m = (lo + hi) >> 1; if (batch[m] <= g) lo = m + 1; else hi = m; }
  float inv = 1.f / fmaxf((float)(lo - start), 1.f);
  float acc = bcls[c];
#pragma unroll 8
  for (int k = 0; k < D; k++) acc += pooled[g * D + k] * inv * Wcls[k * NCLS + c];
  out[g * NCLS + c] = acc;
}

// ---------------------------------------------------------------------------
extern "C" void kernel_launch(void* const* d_in, const int* in_sizes, int n_in,
                              void* d_out, int out_size, void* d_ws, size_t ws_size,
                              hipStream_t stream) {
  const float* x      = (const float*)d_in[0];
  const int*   ei     = (const int*)d_in[1];
  const int*   batch  = (const int*)d_in[2];
  const float* W_rel  = (const float*)d_in[3];
  const float* b_rel  = (const float*)d_in[4];
  const float* W_root = (const float*)d_in[5];
  const float* gamma  = (const float*)d_in[6];
  const float* beta   = (const float*)d_in[7];
  const float* W_cls  = (const float*)d_in[8];
  const float* b_cls  = (const float*)d_in[9];
  float* out = (float*)d_out;

  int E = in_sizes[1] / 2;
  int N = in_sizes[2];
  size_t nd = (size_t)N * D;
  int nbuck = (N + BUCK_SZ - 1) / BUCK_SZ;  // 196 for N=100k (<=256)
  int capB = ((2 * E / nbuck) + 511) & ~511;
  if (capB < 1024) capB = 1024;
  float invN = 1.0f / (float)N;

  // Workspace layout.
  float* bufA    = (float*)d_ws;                 // N*D: fp32 h (layer 2 only)
  float* bufB    = bufA + nd;                    // N*D: msg
  ushort* xbf    = (ushort*)(bufB + nd);         // N*D bf16 x/h chain
  float* stats3  = (float*)(xbf + nd);           // 3 * 2*D  -- zeroed
  float* pooled  = stats3 + 3 * 2 * D;           // NGRAPH*D -- zeroed
  int* gcnt      = (int*)(pooled + NGRAPH * D);  // nbuck -- zeroed
  ushort* wfrag  = (ushort*)(gcnt + ((nbuck + 3) & ~3));  // 3*16384 ushorts
  int* bstart    = (int*)(wfrag + 3 * 16384);    // nbuck+1
  int* row_start = bstart + nbuck + 1;           // N+1
  int* csr_src   = row_start + N + 1;            // E
  int* pk        = csr_src + E;                  // nbuck*capB

  size_t zero_bytes = (size_t)(3 * 2 * D + NGRAPH * D) * 4 +
                      (size_t)nbuck * 4;
  hipMemsetAsync(stats3, 0, zero_bytes, stream);

  // ---- CSR build + weight/x prep (once) ----
  bucket_scatter_kernel<<<(E + EPB - 1) / EPB, 256, 0, stream>>>(
      ei, gcnt, pk, E, capB, nbuck);
  bucket_scan_kernel<<<1, 256, 0, stream>>>(gcnt, bstart, row_start, nbuck, N, capB);
  bucket_place_kernel<<<nbuck, 256, 0, stream>>>(pk, gcnt, bstart, row_start,
                                                 csr_src, N, capB);
  wsplit_kernel<<<3, 256, 0, stream>>>(W_rel, W_root, wfrag);
  xprep_kernel<<<(int)((nd / 8 + 255) / 256), 256, 0, stream>>>(x, xbf, (int)nd);

  // ---- Layers (no bn_finalize: scale/shift computed inline from stats) ----
  const int MM_BLOCKS = 512;
  const int MM_WAVES = MM_BLOCKS * 4;
  int ntiles = (N + 15) / 16;
  for (int l = 0; l < 3; l++) {
    int apply = (l > 0) ? 1 : 0;
    int wbf = (l < 2) ? 1 : 0;
    int wh = (l == 2) ? 1 : 0;
    const float* st_prev = stats3 + (l > 0 ? (l - 1) * 2 * D : 0);
    const float* gm_prev = gamma + (l > 0 ? (l - 1) * D : 0);
    const float* bt_prev = beta + (l > 0 ? (l - 1) * D : 0);
    float* st_cur = stats3 + l * 2 * D;

    gather_kernel<<<(N + 3) / 4, 256, 0, stream>>>(
        xbf, csr_src, row_start, st_prev, gm_prev, bt_prev, invN, apply,
        bufB, N);

    mm_mfma_kernel<<<MM_BLOCKS, 256, 0, stream>>>(
        bufB, x, xbf, wfrag + l * 16384, b_rel + l * D,
        st_prev, gm_prev, bt_prev, invN, apply,
        bufA, xbf /* in-place bf16 h chain */, wh, wbf, st_cur,
        N, ntiles, MM_WAVES);
  }

  norm_relu_pool_kernel<<<(N + 255) / 256, 256, 0, stream>>>(
      bufA, stats3 + 2 * 2 * D, gamma + 2 * D, beta + 2 * D, invN, batch,
      pooled, N);
  cls_kernel<<<(NGRAPH * NCLS + 255) / 256, 256, 0, stream>>>(
      pooled, batch, W_cls, b_cls, out, N);
}